// Round 1
// baseline (114.653 us; speedup 1.0000x reference)
//
#include <hip/hip_runtime.h>

#define EN 9
#define DD 64
#define SS 512
#define NB 16
#define HH 1024
#define NOUT 1152  // EN*DD*2

typedef short bf16x8 __attribute__((ext_vector_type(8)));
typedef short short4v __attribute__((ext_vector_type(4)));
typedef float f32x4 __attribute__((ext_vector_type(4)));

#define GPTR(p) ((const __attribute__((address_space(1))) void*)(p))
#define LPTR(p) ((__attribute__((address_space(3))) void*)(p))

__device__ inline unsigned short f2bf(float f) {
  unsigned int u = __float_as_uint(f);
  return (unsigned short)((u + 0x7FFFu + ((u >> 16) & 1u)) >> 16);
}

// ---------------- prep: W -> Wt (bf16, transposed) + rope tables ----------------
__global__ __launch_bounds__(256) void prep_kernel(
    const float* __restrict__ W, unsigned short* __restrict__ Wt,
    float* __restrict__ ctab, float* __restrict__ stab) {
  if (blockIdx.x < 288u) {
    __shared__ float t[64][65];
    const int k0 = (blockIdx.x / 18) * 64;
    const int n0 = (blockIdx.x % 18) * 64;
    const int r = threadIdx.x >> 6;
    const int c = threadIdx.x & 63;
#pragma unroll
    for (int i = 0; i < 16; ++i) {
      const int kk = (i << 2) + r;
      t[kk][c] = W[(size_t)(k0 + kk) * NOUT + n0 + c];
    }
    __syncthreads();
#pragma unroll
    for (int i = 0; i < 16; ++i) {
      const int nn = (i << 2) + r;
      Wt[(size_t)(n0 + nn) * HH + k0 + c] = f2bf(t[c][nn]);
    }
  } else {
    const int bt = blockIdx.x - 288;
#pragma unroll
    for (int j = 0; j < 4; ++j) {
      const int id = bt * 1024 + j * 256 + threadIdx.x;
      const int s = id >> 5, i = id & 31;
      const float freq = expf(-(float)(2 * i) * (9.210340371976184f / 64.0f));
      const float ang = (float)s * freq;
      ctab[id] = cosf(ang);
      stab[id] = sinf(ang);
    }
  }
}

// ---------------- proj + rope: QK[b][h][{q,k}][s][64] bf16 ----------------
__global__ __launch_bounds__(256, 2) void proj_rope_kernel(
    const float* __restrict__ X, const unsigned short* __restrict__ Wt,
    const float* __restrict__ bias, const float* __restrict__ ctab,
    const float* __restrict__ stab, unsigned short* __restrict__ QK) {
  __shared__ __align__(16) unsigned char sm[32768];  // At[128][64] | Bt[128][64]
  const int tid = threadIdx.x;
  const int lane = tid & 63;
  const int wid = tid >> 6;
  const int wr = wid >> 1, wc = wid & 1;
  const int m0 = blockIdx.y << 7;
  const int n0 = blockIdx.x << 7;

  f32x4 acc[4][4];
#pragma unroll
  for (int i = 0; i < 4; ++i)
#pragma unroll
    for (int j = 0; j < 4; ++j) acc[i][j] = (f32x4){0.f, 0.f, 0.f, 0.f};

  for (int kt = 0; kt < HH; kt += 64) {
    // X tile: 128x64 f32 -> bf16, reg-staged, XOR-swizzled (16B chunk ^ (row&7))
#pragma unroll
    for (int it = 0; it < 8; ++it) {
      const int q = it * 256 + tid;
      const int r = q >> 4, c8 = q & 15;  // c8: 8B unit within row
      const float4 v =
          *(const float4*)(X + (size_t)(m0 + r) * HH + kt + (c8 << 2));
      short4v s4;
      s4[0] = (short)f2bf(v.x);
      s4[1] = (short)f2bf(v.y);
      s4[2] = (short)f2bf(v.z);
      s4[3] = (short)f2bf(v.w);
      const int byte =
          (r << 7) + ((((c8 >> 1) ^ (r & 7)) << 4) | ((c8 & 1) << 3));
      *(short4v*)(sm + byte) = s4;
    }
    // Wt tile: 128x64 bf16 via global_load_lds, pre-swizzled global source
#pragma unroll
    for (int it = 0; it < 4; ++it) {
      const int q = it * 256 + tid;
      const int r = q >> 3, cl = q & 7;
      const int cs = cl ^ (r & 7);
      __builtin_amdgcn_global_load_lds(
          GPTR(Wt + (size_t)(n0 + r) * HH + kt + (cs << 3)),
          LPTR(sm + 16384 + ((it * 256 + wid * 64) << 4)), 16, 0, 0);
    }
    __syncthreads();
#pragma unroll
    for (int kb = 0; kb < 2; ++kb) {
      bf16x8 af[4], bfr[4];
      const int ca = (kb << 2) + (lane >> 4);
#pragma unroll
      for (int i = 0; i < 4; ++i) {
        const int ra = (wr << 6) + (i << 4) + (lane & 15);
        af[i] = *(const bf16x8*)(sm + (ra << 7) + ((ca ^ (ra & 7)) << 4));
        const int rb = (wc << 6) + (i << 4) + (lane & 15);
        bfr[i] =
            *(const bf16x8*)(sm + 16384 + (rb << 7) + ((ca ^ (rb & 7)) << 4));
      }
#pragma unroll
      for (int mi = 0; mi < 4; ++mi)
#pragma unroll
        for (int ni = 0; ni < 4; ++ni)
          acc[mi][ni] = __builtin_amdgcn_mfma_f32_16x16x32_bf16(
              af[mi], bfr[ni], acc[mi][ni], 0, 0, 0);
    }
    __syncthreads();
  }

  // epilogue: bias + rope, write bf16
#pragma unroll
  for (int mi = 0; mi < 4; ++mi) {
#pragma unroll
    for (int ni = 0; ni < 4; ++ni) {
      const int n = n0 + (wc << 6) + (ni << 4) + (lane & 15);
      const float bn = bias[n];
      const int h = n >> 7, t = (n >> 6) & 1, d = n & 63;
      const int i2 = d >> 1;
      const bool ev = (d & 1) == 0;
#pragma unroll
      for (int r = 0; r < 4; ++r) {
        const int m = m0 + (wr << 6) + (mi << 4) + ((lane >> 4) << 2) + r;
        const int s = m & (SS - 1);
        const int bb = m >> 9;
        const float v = acc[mi][ni][r] + bn;
        const float p = __shfl_xor(v, 1);
        const float cs = ctab[(s << 5) + i2];
        const float sn = stab[(s << 5) + i2];
        const float o = ev ? (v * cs - p * sn) : (v * cs + p * sn);
        QK[((((size_t)bb * EN + h) * 2 + t) * SS + s) * DD + d] = f2bf(o);
      }
    }
  }
}

// ---------------- logits: per (b,h), 128x128 tiles of 512x512 ----------------
__global__ __launch_bounds__(256, 2) void logits_kernel(
    const unsigned short* __restrict__ QK, const float* __restrict__ pmask,
    float* __restrict__ out) {
  __shared__ __align__(16) unsigned char sm[32768];  // Q[128][64] | K[128][64]
  const int tid = threadIdx.x;
  const int lane = tid & 63;
  const int wid = tid >> 6;
  const int wr = wid >> 1, wc = wid & 1;
  const int bh = blockIdx.y;
  const int bb = bh / EN;
  const int tm = blockIdx.x >> 2, tn = blockIdx.x & 3;
  const int mq0 = tm << 7, nk0 = tn << 7;
  const unsigned short* Qb = QK + (size_t)bh * 2 * SS * DD;
  const unsigned short* Kb = Qb + SS * DD;

#pragma unroll
  for (int it = 0; it < 4; ++it) {
    const int q = it * 256 + tid;
    const int r = q >> 3, cl = q & 7;
    const int cs = cl ^ (r & 7);
    __builtin_amdgcn_global_load_lds(
        GPTR(Qb + (size_t)(mq0 + r) * DD + (cs << 3)),
        LPTR(sm + ((it * 256 + wid * 64) << 4)), 16, 0, 0);
    __builtin_amdgcn_global_load_lds(
        GPTR(Kb + (size_t)(nk0 + r) * DD + (cs << 3)),
        LPTR(sm + 16384 + ((it * 256 + wid * 64) << 4)), 16, 0, 0);
  }
  __syncthreads();

  f32x4 acc[4][4];
#pragma unroll
  for (int i = 0; i < 4; ++i)
#pragma unroll
    for (int j = 0; j < 4; ++j) acc[i][j] = (f32x4){0.f, 0.f, 0.f, 0.f};

#pragma unroll
  for (int kb = 0; kb < 2; ++kb) {
    bf16x8 af[4], bfr[4];
    const int ca = (kb << 2) + (lane >> 4);
#pragma unroll
    for (int i = 0; i < 4; ++i) {
      const int ra = (wr << 6) + (i << 4) + (lane & 15);
      af[i] = *(const bf16x8*)(sm + (ra << 7) + ((ca ^ (ra & 7)) << 4));
      const int rb = (wc << 6) + (i << 4) + (lane & 15);
      bfr[i] =
          *(const bf16x8*)(sm + 16384 + (rb << 7) + ((ca ^ (rb & 7)) << 4));
    }
#pragma unroll
    for (int mi = 0; mi < 4; ++mi)
#pragma unroll
      for (int ni = 0; ni < 4; ++ni)
        acc[mi][ni] = __builtin_amdgcn_mfma_f32_16x16x32_bf16(
            af[mi], bfr[ni], acc[mi][ni], 0, 0, 0);
  }

#pragma unroll
  for (int mi = 0; mi < 4; ++mi) {
#pragma unroll
    for (int ni = 0; ni < 4; ++ni) {
      const int n = nk0 + (wc << 6) + (ni << 4) + (lane & 15);
      const float pd = pmask[bb * SS + n];
      const float sub = (1.0f - pd) * 1e12f;
#pragma unroll
      for (int r = 0; r < 4; ++r) {
        const int m = mq0 + (wr << 6) + (mi << 4) + ((lane >> 4) << 2) + r;
        float v = acc[mi][ni][r] * pd - sub;
        if (m > n) v -= 1e12f;
        out[((size_t)bh * SS + m) * SS + n] = v * 0.125f;
      }
    }
  }
}

extern "C" void kernel_launch(void* const* d_in, const int* in_sizes, int n_in,
                              void* d_out, int out_size, void* d_ws,
                              size_t ws_size, hipStream_t stream) {
  const float* X = (const float*)d_in[0];
  const float* pm = (const float*)d_in[1];
  const float* W = (const float*)d_in[2];
  const float* bias = (const float*)d_in[3];
  float* out = (float*)d_out;
  unsigned char* ws = (unsigned char*)d_ws;
  unsigned short* Wt = (unsigned short*)ws;                       // 2,359,296 B
  float* ctab = (float*)(ws + 2359296);                           // 65,536 B
  float* stab = (float*)(ws + 2359296 + 65536);                   // 65,536 B
  unsigned short* QK = (unsigned short*)(ws + 2359296 + 131072);  // 18,874,368 B

  prep_kernel<<<dim3(304), dim3(256), 0, stream>>>(W, Wt, ctab, stab);
  proj_rope_kernel<<<dim3(9, 64), dim3(256), 0, stream>>>(X, Wt, bias, ctab,
                                                          stab, QK);
  logits_kernel<<<dim3(16, 144), dim3(256), 0, stream>>>(QK, pm, out);
}

// Round 2
// 77.818 us; speedup vs baseline: 1.4733x; 1.4733x over previous
//
#include <hip/hip_runtime.h>

#define EN 9
#define DD 64
#define SS 512
#define NB 16
#define HH 1024
#define NOUT 1152  // EN*DD*2

typedef short bf16x8 __attribute__((ext_vector_type(8)));
typedef short short4v __attribute__((ext_vector_type(4)));
typedef float f32x4 __attribute__((ext_vector_type(4)));

#define GPTR(p) ((const __attribute__((address_space(1))) void*)(p))
#define LPTR(p) ((__attribute__((address_space(3))) void*)(p))

__device__ inline unsigned short f2bf(float f) {
  unsigned int u = __float_as_uint(f);
  return (unsigned short)((u + 0x7FFFu + ((u >> 16) & 1u)) >> 16);
}

// ---- prep: W -> Wt (bf16 transposed), X -> Xb (bf16), rope tables ----
__global__ __launch_bounds__(256) void prep_kernel(
    const float* __restrict__ W, const float* __restrict__ X,
    unsigned short* __restrict__ Wt, unsigned short* __restrict__ Xb,
    float* __restrict__ ctab, float* __restrict__ stab) {
  if (blockIdx.x < 288u) {
    __shared__ float t[64][65];
    const int k0 = (blockIdx.x / 18) * 64;
    const int n0 = (blockIdx.x % 18) * 64;
    const int r = threadIdx.x >> 6;
    const int c = threadIdx.x & 63;
#pragma unroll
    for (int i = 0; i < 16; ++i) {
      const int kk = (i << 2) + r;
      t[kk][c] = W[(size_t)(k0 + kk) * NOUT + n0 + c];
    }
    __syncthreads();
#pragma unroll
    for (int i = 0; i < 16; ++i) {
      const int nn = (i << 2) + r;
      Wt[(size_t)(n0 + nn) * HH + k0 + c] = f2bf(t[c][nn]);
    }
  } else if (blockIdx.x < 304u) {
    const int bt = blockIdx.x - 288;
#pragma unroll
    for (int j = 0; j < 4; ++j) {
      const int id = bt * 1024 + j * 256 + threadIdx.x;
      const int s = id >> 5, i = id & 31;
      const float freq = expf(-(float)(2 * i) * (9.210340371976184f / 64.0f));
      const float ang = (float)s * freq;
      ctab[id] = cosf(ang);
      stab[id] = sinf(ang);
    }
  } else {
    // X f32 -> bf16, 4096 elements per block
    const int bt = blockIdx.x - 304;
    const size_t base = (size_t)bt * 4096;
#pragma unroll
    for (int j = 0; j < 4; ++j) {
      const size_t idx = base + (size_t)((j << 8) + threadIdx.x) * 4;
      const float4 v = *(const float4*)(X + idx);
      short4v s4;
      s4[0] = (short)f2bf(v.x);
      s4[1] = (short)f2bf(v.y);
      s4[2] = (short)f2bf(v.z);
      s4[3] = (short)f2bf(v.w);
      *(short4v*)(Xb + idx) = s4;
    }
  }
}

// ---- proj + rope: QK[b][h][{q,k}][s][64] bf16, 2-phase dbuf pipeline ----
__global__ __launch_bounds__(256, 2) void proj_rope_kernel(
    const unsigned short* __restrict__ Xb,
    const unsigned short* __restrict__ Wt, const float* __restrict__ bias,
    const float* __restrict__ ctab, const float* __restrict__ stab,
    unsigned short* __restrict__ QK) {
  // 2 bufs x (A 128x64 bf16 = 16KB | B 128x64 = 16KB)
  __shared__ __align__(16) unsigned char sm[65536];
  const int tid = threadIdx.x;
  const int lane = tid & 63;
  const int wid = tid >> 6;
  const int wr = wid >> 1, wc = wid & 1;
  const int m0 = blockIdx.x << 7;  // 64 m-tiles (fast dim: share Wt panel)
  const int n0 = blockIdx.y << 7;  // 9 n-tiles

  const int r_st = tid >> 3;   // staging row within 32-row chunk
  const int cl_st = tid & 7;   // staging 16B-chunk within row

  f32x4 acc[4][4];
#pragma unroll
  for (int i = 0; i < 4; ++i)
#pragma unroll
    for (int j = 0; j < 4; ++j) acc[i][j] = (f32x4){0.f, 0.f, 0.f, 0.f};

#define STAGE(BUF, KT)                                                        \
  {                                                                           \
    const int kt_ = (KT);                                                     \
    unsigned char* dst_ = sm + (BUF)*32768;                                   \
    _Pragma("unroll") for (int it = 0; it < 4; ++it) {                        \
      const int r_ = (it << 5) + r_st;                                        \
      const int cs_ = cl_st ^ (r_ & 7);                                       \
      __builtin_amdgcn_global_load_lds(                                       \
          GPTR(Xb + (size_t)(m0 + r_) * HH + kt_ + (cs_ << 3)),               \
          LPTR(dst_ + (((it << 8) + (wid << 6)) << 4)), 16, 0, 0);            \
      __builtin_amdgcn_global_load_lds(                                       \
          GPTR(Wt + (size_t)(n0 + r_) * HH + kt_ + (cs_ << 3)),               \
          LPTR(dst_ + 16384 + (((it << 8) + (wid << 6)) << 4)), 16, 0, 0);    \
    }                                                                         \
  }

#define COMPUTE(BUF)                                                          \
  {                                                                           \
    const unsigned char* smc_ = sm + (BUF)*32768;                             \
    _Pragma("unroll") for (int kb = 0; kb < 2; ++kb) {                        \
      bf16x8 af[4], bfr[4];                                                   \
      const int ca = (kb << 2) + (lane >> 4);                                 \
      _Pragma("unroll") for (int i = 0; i < 4; ++i) {                         \
        const int ra = (wr << 6) + (i << 4) + (lane & 15);                    \
        af[i] = *(const bf16x8*)(smc_ + (ra << 7) + ((ca ^ (ra & 7)) << 4));  \
        const int rb = (wc << 6) + (i << 4) + (lane & 15);                    \
        bfr[i] =                                                              \
            *(const bf16x8*)(smc_ + 16384 + (rb << 7) + ((ca ^ (rb & 7))      \
                                                         << 4));              \
      }                                                                       \
      _Pragma("unroll") for (int mi = 0; mi < 4; ++mi)                        \
          _Pragma("unroll") for (int ni = 0; ni < 4; ++ni) acc[mi][ni] =      \
          __builtin_amdgcn_mfma_f32_16x16x32_bf16(af[mi], bfr[ni],            \
                                                  acc[mi][ni], 0, 0, 0);      \
    }                                                                         \
  }

  STAGE(0, 0)
  __syncthreads();  // compiler drains vmcnt(0) before s_barrier
#pragma unroll 1
  for (int t = 0; t < 15; ++t) {
    STAGE((t & 1) ^ 1, (t + 1) << 6)  // prefetch next K-tile
    COMPUTE(t & 1)
    __syncthreads();  // drains this STAGE; protects buf just read
  }
  COMPUTE(1)

  // epilogue: bias + rope, write bf16
#pragma unroll
  for (int mi = 0; mi < 4; ++mi) {
#pragma unroll
    for (int ni = 0; ni < 4; ++ni) {
      const int n = n0 + (wc << 6) + (ni << 4) + (lane & 15);
      const float bn = bias[n];
      const int h = n >> 7, t = (n >> 6) & 1, d = n & 63;
      const int i2 = d >> 1;
      const bool ev = (d & 1) == 0;
#pragma unroll
      for (int r = 0; r < 4; ++r) {
        const int m = m0 + (wr << 6) + (mi << 4) + ((lane >> 4) << 2) + r;
        const int s = m & (SS - 1);
        const int bb = m >> 9;
        const float v = acc[mi][ni][r] + bn;
        const float p = __shfl_xor(v, 1);
        const float cs = ctab[(s << 5) + i2];
        const float sn = stab[(s << 5) + i2];
        const float o = ev ? (v * cs - p * sn) : (v * cs + p * sn);
        QK[((((size_t)bb * EN + h) * 2 + t) * SS + s) * DD + d] = f2bf(o);
      }
    }
  }
}

// ---- logits: per (b,h), 128x128 tiles of 512x512 ----
__global__ __launch_bounds__(256, 2) void logits_kernel(
    const unsigned short* __restrict__ QK, const float* __restrict__ pmask,
    float* __restrict__ out) {
  __shared__ __align__(16) unsigned char sm[32768];  // Q[128][64] | K[128][64]
  const int tid = threadIdx.x;
  const int lane = tid & 63;
  const int wid = tid >> 6;
  const int wr = wid >> 1, wc = wid & 1;
  const int bh = blockIdx.y;
  const int bb = bh / EN;
  const int tm = blockIdx.x >> 2, tn = blockIdx.x & 3;
  const int mq0 = tm << 7, nk0 = tn << 7;
  const unsigned short* Qb = QK + (size_t)bh * 2 * SS * DD;
  const unsigned short* Kb = Qb + SS * DD;

#pragma unroll
  for (int it = 0; it < 4; ++it) {
    const int q = it * 256 + tid;
    const int r = q >> 3, cl = q & 7;
    const int cs = cl ^ (r & 7);
    __builtin_amdgcn_global_load_lds(
        GPTR(Qb + (size_t)(mq0 + r) * DD + (cs << 3)),
        LPTR(sm + ((it * 256 + wid * 64) << 4)), 16, 0, 0);
    __builtin_amdgcn_global_load_lds(
        GPTR(Kb + (size_t)(nk0 + r) * DD + (cs << 3)),
        LPTR(sm + 16384 + ((it * 256 + wid * 64) << 4)), 16, 0, 0);
  }
  __syncthreads();

  f32x4 acc[4][4];
#pragma unroll
  for (int i = 0; i < 4; ++i)
#pragma unroll
    for (int j = 0; j < 4; ++j) acc[i][j] = (f32x4){0.f, 0.f, 0.f, 0.f};

#pragma unroll
  for (int kb = 0; kb < 2; ++kb) {
    bf16x8 af[4], bfr[4];
    const int ca = (kb << 2) + (lane >> 4);
#pragma unroll
    for (int i = 0; i < 4; ++i) {
      const int ra = (wr << 6) + (i << 4) + (lane & 15);
      af[i] = *(const bf16x8*)(sm + (ra << 7) + ((ca ^ (ra & 7)) << 4));
      const int rb = (wc << 6) + (i << 4) + (lane & 15);
      bfr[i] =
          *(const bf16x8*)(sm + 16384 + (rb << 7) + ((ca ^ (rb & 7)) << 4));
    }
#pragma unroll
    for (int mi = 0; mi < 4; ++mi)
#pragma unroll
      for (int ni = 0; ni < 4; ++ni)
        acc[mi][ni] = __builtin_amdgcn_mfma_f32_16x16x32_bf16(
            af[mi], bfr[ni], acc[mi][ni], 0, 0, 0);
  }

#pragma unroll
  for (int mi = 0; mi < 4; ++mi) {
#pragma unroll
    for (int ni = 0; ni < 4; ++ni) {
      const int n = nk0 + (wc << 6) + (ni << 4) + (lane & 15);
      const float pd = pmask[bb * SS + n];
      const float sub = (1.0f - pd) * 1e12f;
#pragma unroll
      for (int r = 0; r < 4; ++r) {
        const int m = mq0 + (wr << 6) + (mi << 4) + ((lane >> 4) << 2) + r;
        float v = acc[mi][ni][r] * pd - sub;
        if (m > n) v -= 1e12f;
        out[((size_t)bh * SS + m) * SS + n] = v * 0.125f;
      }
    }
  }
}

extern "C" void kernel_launch(void* const* d_in, const int* in_sizes, int n_in,
                              void* d_out, int out_size, void* d_ws,
                              size_t ws_size, hipStream_t stream) {
  const float* X = (const float*)d_in[0];
  const float* pm = (const float*)d_in[1];
  const float* W = (const float*)d_in[2];
  const float* bias = (const float*)d_in[3];
  float* out = (float*)d_out;
  unsigned char* ws = (unsigned char*)d_ws;
  unsigned short* QK = (unsigned short*)ws;                 // 18,874,368 B
  unsigned short* Wt = (unsigned short*)(ws + 18874368);    // 2,359,296 B
  float* ctab = (float*)(ws + 21233664);                    // 65,536 B
  float* stab = (float*)(ws + 21299200);                    // 65,536 B
  unsigned short* Xb = (unsigned short*)(ws + 21364736);    // 16,777,216 B

  prep_kernel<<<dim3(2352), dim3(256), 0, stream>>>(W, X, Wt, Xb, ctab, stab);
  proj_rope_kernel<<<dim3(64, 9), dim3(256), 0, stream>>>(Xb, Wt, bias, ctab,
                                                          stab, QK);
  logits_kernel<<<dim3(16, 144), dim3(256), 0, stream>>>(QK, pm, out);
}

// Round 3
// 71.845 us; speedup vs baseline: 1.5958x; 1.0831x over previous
//
#include <hip/hip_runtime.h>

#define EN 9
#define DD 64
#define SS 512
#define NB 16
#define HH 1024
#define NOUT 1152  // EN*DD*2

typedef short bf16x8 __attribute__((ext_vector_type(8)));
typedef short short4v __attribute__((ext_vector_type(4)));
typedef float f32x4 __attribute__((ext_vector_type(4)));

#define GPTR(p) ((const __attribute__((address_space(1))) void*)(p))
#define LPTR(p) ((__attribute__((address_space(3))) void*)(p))

__device__ inline unsigned short f2bf(float f) {
  unsigned int u = __float_as_uint(f);
  return (unsigned short)((u + 0x7FFFu + ((u >> 16) & 1u)) >> 16);
}

// ---- prep: W -> Wt (bf16 transposed), X -> Xb (bf16), rope tables ----
__global__ __launch_bounds__(256) void prep_kernel(
    const float* __restrict__ W, const float* __restrict__ X,
    unsigned short* __restrict__ Wt, unsigned short* __restrict__ Xb,
    float* __restrict__ ctab, float* __restrict__ stab) {
  if (blockIdx.x < 288u) {
    __shared__ float t[64][65];
    const int k0 = (blockIdx.x / 18) * 64;
    const int n0 = (blockIdx.x % 18) * 64;
    const int r = threadIdx.x >> 6;
    const int c = threadIdx.x & 63;
#pragma unroll
    for (int i = 0; i < 16; ++i) {
      const int kk = (i << 2) + r;
      t[kk][c] = W[(size_t)(k0 + kk) * NOUT + n0 + c];
    }
    __syncthreads();
#pragma unroll
    for (int i = 0; i < 16; ++i) {
      const int nn = (i << 2) + r;
      Wt[(size_t)(n0 + nn) * HH + k0 + c] = f2bf(t[c][nn]);
    }
  } else if (blockIdx.x < 304u) {
    const int bt = blockIdx.x - 288;
#pragma unroll
    for (int j = 0; j < 4; ++j) {
      const int id = bt * 1024 + j * 256 + threadIdx.x;
      const int s = id >> 5, i = id & 31;
      const float freq = expf(-(float)(2 * i) * (9.210340371976184f / 64.0f));
      const float ang = (float)s * freq;
      ctab[id] = cosf(ang);
      stab[id] = sinf(ang);
    }
  } else {
    // X f32 -> bf16, 4096 elements per block
    const int bt = blockIdx.x - 304;
    const size_t base = (size_t)bt * 4096;
#pragma unroll
    for (int j = 0; j < 4; ++j) {
      const size_t idx = base + (size_t)((j << 8) + threadIdx.x) * 4;
      const float4 v = *(const float4*)(X + idx);
      short4v s4;
      s4[0] = (short)f2bf(v.x);
      s4[1] = (short)f2bf(v.y);
      s4[2] = (short)f2bf(v.z);
      s4[3] = (short)f2bf(v.w);
      *(short4v*)(Xb + idx) = s4;
    }
  }
}

// ---- proj + rope: QK[b][h][{q,k}][s][64] bf16, counted-vmcnt dbuf ----
__global__ __launch_bounds__(256, 2) void proj_rope_kernel(
    const unsigned short* __restrict__ Xb,
    const unsigned short* __restrict__ Wt, const float* __restrict__ bias,
    const float* __restrict__ ctab, const float* __restrict__ stab,
    unsigned short* __restrict__ QK) {
  // 2 bufs x (A 128x64 bf16 = 16KB | B 128x64 = 16KB)
  __shared__ __align__(16) unsigned char sm[65536];
  const int tid = threadIdx.x;
  const int lane = tid & 63;
  const int wid = tid >> 6;
  const int wr = wid >> 1, wc = wid & 1;
  // XCD-chunked remap (8 XCDs x 72 blocks), n-fast inner order:
  // each XCD keeps Wt (2.3MB) + its 8 Xb panels resident in L2.
  const int f = blockIdx.x;
  const int wkr = (f & 7) * 72 + (f >> 3);
  const int m0 = (wkr / 9) << 7;
  const int n0 = (wkr % 9) << 7;

  const int r_st = tid >> 3;  // staging row within 32-row chunk
  const int cl_st = tid & 7;  // staging 16B-chunk within row

  f32x4 acc[4][4];
#pragma unroll
  for (int i = 0; i < 4; ++i)
#pragma unroll
    for (int j = 0; j < 4; ++j) acc[i][j] = (f32x4){0.f, 0.f, 0.f, 0.f};

#define STAGE(BUF, KT)                                                        \
  {                                                                           \
    const int kt_ = (KT);                                                     \
    unsigned char* dst_ = sm + (BUF)*32768;                                   \
    _Pragma("unroll") for (int it = 0; it < 4; ++it) {                        \
      const int r_ = (it << 5) + r_st;                                        \
      const int cs_ = cl_st ^ (r_ & 7);                                       \
      __builtin_amdgcn_global_load_lds(                                       \
          GPTR(Xb + (size_t)(m0 + r_) * HH + kt_ + (cs_ << 3)),               \
          LPTR(dst_ + (((it << 8) + (wid << 6)) << 4)), 16, 0, 0);            \
      __builtin_amdgcn_global_load_lds(                                       \
          GPTR(Wt + (size_t)(n0 + r_) * HH + kt_ + (cs_ << 3)),               \
          LPTR(dst_ + 16384 + (((it << 8) + (wid << 6)) << 4)), 16, 0, 0);    \
    }                                                                         \
  }

#define COMPUTE(BUF)                                                          \
  {                                                                           \
    const unsigned char* smc_ = sm + (BUF)*32768;                             \
    _Pragma("unroll") for (int kb = 0; kb < 2; ++kb) {                        \
      bf16x8 af[4], bfr[4];                                                   \
      const int ca = (kb << 2) + (lane >> 4);                                 \
      _Pragma("unroll") for (int i = 0; i < 4; ++i) {                         \
        const int ra = (wr << 6) + (i << 4) + (lane & 15);                    \
        af[i] = *(const bf16x8*)(smc_ + (ra << 7) + ((ca ^ (ra & 7)) << 4));  \
        const int rb = (wc << 6) + (i << 4) + (lane & 15);                    \
        bfr[i] =                                                              \
            *(const bf16x8*)(smc_ + 16384 + (rb << 7) + ((ca ^ (rb & 7))      \
                                                         << 4));              \
      }                                                                       \
      _Pragma("unroll") for (int mi = 0; mi < 4; ++mi)                        \
          _Pragma("unroll") for (int ni = 0; ni < 4; ++ni) acc[mi][ni] =      \
          __builtin_amdgcn_mfma_f32_16x16x32_bf16(af[mi], bfr[ni],            \
                                                  acc[mi][ni], 0, 0, 0);      \
    }                                                                         \
  }

  STAGE(0, 0)  // 8 loads in flight
#pragma unroll 1
  for (int t = 0; t < 15; ++t) {
    STAGE((t + 1) & 1, (t + 1) << 6)  // +8 loads (16 outstanding)
    asm volatile("s_waitcnt vmcnt(8)" ::: "memory");  // tile t landed
    __builtin_amdgcn_s_barrier();                     // all waves see it
    __builtin_amdgcn_sched_barrier(0);
    COMPUTE(t & 1)
    __builtin_amdgcn_sched_barrier(0);
    __builtin_amdgcn_s_barrier();  // reads of buf t done before overwrite
  }
  asm volatile("s_waitcnt vmcnt(0)" ::: "memory");
  __builtin_amdgcn_s_barrier();
  __builtin_amdgcn_sched_barrier(0);
  COMPUTE(1)

  // epilogue: bias + rope, write bf16
#pragma unroll
  for (int mi = 0; mi < 4; ++mi) {
#pragma unroll
    for (int ni = 0; ni < 4; ++ni) {
      const int n = n0 + (wc << 6) + (ni << 4) + (lane & 15);
      const float bn = bias[n];
      const int h = n >> 7, t = (n >> 6) & 1, d = n & 63;
      const int i2 = d >> 1;
      const bool ev = (d & 1) == 0;
#pragma unroll
      for (int r = 0; r < 4; ++r) {
        const int m = m0 + (wr << 6) + (mi << 4) + ((lane >> 4) << 2) + r;
        const int s = m & (SS - 1);
        const int bb = m >> 9;
        const float v = acc[mi][ni][r] + bn;
        const float p = __shfl_xor(v, 1);
        const float cs = ctab[(s << 5) + i2];
        const float sn = stab[(s << 5) + i2];
        const float o = ev ? (v * cs - p * sn) : (v * cs + p * sn);
        QK[((((size_t)bb * EN + h) * 2 + t) * SS + s) * DD + d] = f2bf(o);
      }
    }
  }
}

// ---- logits: per (b,h), 128x128 tiles of 512x512 ----
__global__ __launch_bounds__(256, 4) void logits_kernel(
    const unsigned short* __restrict__ QK, const float* __restrict__ pmask,
    float* __restrict__ out) {
  __shared__ __align__(16) unsigned char sm[32768];  // Q[128][64] | K[128][64]
  const int tid = threadIdx.x;
  const int lane = tid & 63;
  const int wid = tid >> 6;
  const int wr = wid >> 1, wc = wid & 1;
  // XCD-chunked remap: 2304 = 8 x 288; each XCD gets 18 contiguous bh
  // (2.4MB of QK -> L2-resident).
  const int f = blockIdx.x;
  const int wkr = (f & 7) * 288 + (f >> 3);
  const int bh = wkr >> 4;
  const int bb = bh / EN;
  const int tm = (wkr >> 2) & 3, tn = wkr & 3;
  const int mq0 = tm << 7, nk0 = tn << 7;
  const unsigned short* Qb = QK + (size_t)bh * 2 * SS * DD;
  const unsigned short* Kb = Qb + SS * DD;

#pragma unroll
  for (int it = 0; it < 4; ++it) {
    const int q = it * 256 + tid;
    const int r = q >> 3, cl = q & 7;
    const int cs = cl ^ (r & 7);
    __builtin_amdgcn_global_load_lds(
        GPTR(Qb + (size_t)(mq0 + r) * DD + (cs << 3)),
        LPTR(sm + ((it * 256 + wid * 64) << 4)), 16, 0, 0);
    __builtin_amdgcn_global_load_lds(
        GPTR(Kb + (size_t)(nk0 + r) * DD + (cs << 3)),
        LPTR(sm + 16384 + ((it * 256 + wid * 64) << 4)), 16, 0, 0);
  }
  __syncthreads();

  f32x4 acc[4][4];
#pragma unroll
  for (int i = 0; i < 4; ++i)
#pragma unroll
    for (int j = 0; j < 4; ++j) acc[i][j] = (f32x4){0.f, 0.f, 0.f, 0.f};

#pragma unroll
  for (int kb = 0; kb < 2; ++kb) {
    bf16x8 af[4], bfr[4];
    const int ca = (kb << 2) + (lane >> 4);
#pragma unroll
    for (int i = 0; i < 4; ++i) {
      const int ra = (wr << 6) + (i << 4) + (lane & 15);
      af[i] = *(const bf16x8*)(sm + (ra << 7) + ((ca ^ (ra & 7)) << 4));
      const int rb = (wc << 6) + (i << 4) + (lane & 15);
      bfr[i] =
          *(const bf16x8*)(sm + 16384 + (rb << 7) + ((ca ^ (rb & 7)) << 4));
    }
#pragma unroll
    for (int mi = 0; mi < 4; ++mi)
#pragma unroll
      for (int ni = 0; ni < 4; ++ni)
        acc[mi][ni] = __builtin_amdgcn_mfma_f32_16x16x32_bf16(
            af[mi], bfr[ni], acc[mi][ni], 0, 0, 0);
  }

#pragma unroll
  for (int mi = 0; mi < 4; ++mi) {
#pragma unroll
    for (int ni = 0; ni < 4; ++ni) {
      const int n = nk0 + (wc << 6) + (ni << 4) + (lane & 15);
      const float pd = pmask[bb * SS + n];
      const float sub = (1.0f - pd) * 1e12f;
#pragma unroll
      for (int r = 0; r < 4; ++r) {
        const int m = mq0 + (wr << 6) + (mi << 4) + ((lane >> 4) << 2) + r;
        float v = acc[mi][ni][r] * pd - sub;
        if (m > n) v -= 1e12f;
        out[((size_t)bh * SS + m) * SS + n] = v * 0.125f;
      }
    }
  }
}

extern "C" void kernel_launch(void* const* d_in, const int* in_sizes, int n_in,
                              void* d_out, int out_size, void* d_ws,
                              size_t ws_size, hipStream_t stream) {
  const float* X = (const float*)d_in[0];
  const float* pm = (const float*)d_in[1];
  const float* W = (const float*)d_in[2];
  const float* bias = (const float*)d_in[3];
  float* out = (float*)d_out;
  unsigned char* ws = (unsigned char*)d_ws;
  unsigned short* QK = (unsigned short*)ws;               // 18,874,368 B
  unsigned short* Wt = (unsigned short*)(ws + 18874368);  // 2,359,296 B
  float* ctab = (float*)(ws + 21233664);                  // 65,536 B
  float* stab = (float*)(ws + 21299200);                  // 65,536 B
  unsigned short* Xb = (unsigned short*)(ws + 21364736);  // 16,777,216 B

  prep_kernel<<<dim3(2352), dim3(256), 0, stream>>>(W, X, Wt, Xb, ctab, stab);
  proj_rope_kernel<<<dim3(576), dim3(256), 0, stream>>>(Xb, Wt, bias, ctab,
                                                        stab, QK);
  logits_kernel<<<dim3(2304), dim3(256), 0, stream>>>(QK, pm, out);
}

// Round 4
// 62.951 us; speedup vs baseline: 1.8213x; 1.1413x over previous
//
#include <hip/hip_runtime.h>

#define EN 9
#define DD 64
#define SS 512
#define HH 1024
#define NOUT 1152  // EN*DD*2

typedef float f32x4 __attribute__((ext_vector_type(4)));

#define GPTR(p) ((const __attribute__((address_space(1))) void*)(p))
#define LPTR(p) ((__attribute__((address_space(3))) void*)(p))

__device__ inline unsigned short f2bf(float f) {
  unsigned int u = __float_as_uint(f);
  return (unsigned short)((u + 0x7FFFu + ((u >> 16) & 1u)) >> 16);
}

__device__ inline int pk4_fp8(float a, float b, float c, float d) {
  int v = __builtin_amdgcn_cvt_pk_fp8_f32(a, b, 0, false);
  v = __builtin_amdgcn_cvt_pk_fp8_f32(c, d, v, true);
  return v;
}

// ---- prep: W -> Wf8 (e4m3, transposed, 8B-chunk XOR-swizzled),
//            X -> Xf8 (e4m3, 8B-chunk XOR-swizzled), rope tables ----
__global__ __launch_bounds__(256) void prep_kernel(
    const float* __restrict__ W, const float* __restrict__ X,
    unsigned char* __restrict__ Wf8, unsigned char* __restrict__ Xf8,
    float* __restrict__ ctab, float* __restrict__ stab) {
  if (blockIdx.x < 288u) {
    __shared__ float t[64][65];
    const int k0 = (blockIdx.x / 18) * 64;
    const int n0 = (blockIdx.x % 18) * 64;
    const int r = threadIdx.x >> 6;
    const int c = threadIdx.x & 63;
#pragma unroll
    for (int i = 0; i < 16; ++i) {
      const int kk = (i << 2) + r;
      t[kk][c] = W[(size_t)(k0 + kk) * NOUT + n0 + c];
    }
    __syncthreads();
#pragma unroll
    for (int i = 0; i < 2; ++i) {
      const int p = (i << 8) + threadIdx.x;  // 0..511
      const int n = p >> 3, cc = p & 7;
      const int kk = cc << 3;
      const int lo = pk4_fp8(t[kk][n], t[kk + 1][n], t[kk + 2][n], t[kk + 3][n]);
      const int hi =
          pk4_fp8(t[kk + 4][n], t[kk + 5][n], t[kk + 6][n], t[kk + 7][n]);
      const int gn = n0 + n;
      int2 v;
      v.x = lo;
      v.y = hi;
      *(int2*)(Wf8 + (size_t)gn * HH + k0 + ((cc ^ (gn & 7)) << 3)) = v;
    }
  } else if (blockIdx.x < 304u) {
    const int bt = blockIdx.x - 288;
#pragma unroll
    for (int j = 0; j < 4; ++j) {
      const int id = bt * 1024 + j * 256 + threadIdx.x;
      const int s = id >> 5, i = id & 31;
      const float freq = expf(-(float)(2 * i) * (9.210340371976184f / 64.0f));
      const float ang = (float)s * freq;
      ctab[id] = cosf(ang);
      stab[id] = sinf(ang);
    }
  } else {
    // X f32 -> fp8, 8-elem chunks; 1024 chunks per block
    const int bt = blockIdx.x - 304;
#pragma unroll
    for (int j = 0; j < 4; ++j) {
      const int C = bt * 1024 + (j << 8) + threadIdx.x;  // chunk id
      const int row = C >> 7, c = C & 127;               // chunk-in-row
      const float4 v0 = *(const float4*)(X + (size_t)C * 8);
      const float4 v1 = *(const float4*)(X + (size_t)C * 8 + 4);
      int2 v;
      v.x = pk4_fp8(v0.x, v0.y, v0.z, v0.w);
      v.y = pk4_fp8(v1.x, v1.y, v1.z, v1.w);
      *(int2*)(Xf8 + (size_t)row * HH + ((c >> 3) << 6) +
               (((c ^ row) & 7) << 3)) = v;
    }
  }
}

// ---- proj + rope (fp8 MFMA): QK[b][h][{q,k}][s][64] bf16 ----
__global__ __launch_bounds__(256, 4) void proj_rope_kernel(
    const unsigned char* __restrict__ Xf8, const unsigned char* __restrict__ Wf8,
    const float* __restrict__ bias, const float* __restrict__ ctab,
    const float* __restrict__ stab, unsigned short* __restrict__ QK) {
  // 2 bufs x (A 128x64 fp8 = 8KB | B 8KB)
  __shared__ __align__(16) unsigned char sm[32768];
  const int tid = threadIdx.x;
  const int lane = tid & 63;
  const int wid = tid >> 6;
  const int wr = wid >> 1, wc = wid & 1;
  // XCD-chunked remap (8 XCDs x 72 blocks), n-fast inner order.
  const int f = blockIdx.x;
  const int wkr = (f & 7) * 72 + (f >> 3);
  const int m0 = (wkr / 9) << 7;
  const int n0 = (wkr % 9) << 7;

  f32x4 acc[4][4];
#pragma unroll
  for (int i = 0; i < 4; ++i)
#pragma unroll
    for (int j = 0; j < 4; ++j) acc[i][j] = (f32x4){0.f, 0.f, 0.f, 0.f};

  // staging: unit u = it*256+tid covers (row u>>2, 16B-granule u&3); LDS linear.
#define STAGE(BUF, KT)                                                       \
  {                                                                          \
    const int kt_ = (KT);                                                    \
    unsigned char* dst_ = sm + (BUF)*16384;                                  \
    _Pragma("unroll") for (int it = 0; it < 2; ++it) {                       \
      const int u_ = (it << 8) + tid;                                        \
      const int r_ = u_ >> 2, g_ = u_ & 3;                                   \
      __builtin_amdgcn_global_load_lds(                                      \
          GPTR(Xf8 + (size_t)(m0 + r_) * HH + kt_ + (g_ << 4)),              \
          LPTR(dst_ + (((it << 8) + (wid << 6)) << 4)), 16, 0, 0);           \
      __builtin_amdgcn_global_load_lds(                                      \
          GPTR(Wf8 + (size_t)(n0 + r_) * HH + kt_ + (g_ << 4)),              \
          LPTR(dst_ + 8192 + (((it << 8) + (wid << 6)) << 4)), 16, 0, 0);    \
    }                                                                        \
  }

#define COMPUTE(BUF)                                                         \
  {                                                                          \
    const unsigned char* smc_ = sm + (BUF)*16384;                            \
    __builtin_amdgcn_s_setprio(1);                                           \
    _Pragma("unroll") for (int kb = 0; kb < 2; ++kb) {                       \
      long aL[4], bL[4];                                                     \
      const int c8 = (kb << 2) + (lane >> 4);                                \
      _Pragma("unroll") for (int i = 0; i < 4; ++i) {                        \
        const int ra = (wr << 6) + (i << 4) + (lane & 15);                   \
        aL[i] = *(const long*)(smc_ + (ra << 6) + (((c8 ^ ra) & 7) << 3));   \
        const int rb = (wc << 6) + (i << 4) + (lane & 15);                   \
        bL[i] = *(const long*)(smc_ + 8192 + (rb << 6) +                     \
                               (((c8 ^ rb) & 7) << 3));                      \
      }                                                                      \
      _Pragma("unroll") for (int mi = 0; mi < 4; ++mi)                       \
          _Pragma("unroll") for (int ni = 0; ni < 4; ++ni) acc[mi][ni] =     \
          __builtin_amdgcn_mfma_f32_16x16x32_fp8_fp8(aL[mi], bL[ni],         \
                                                     acc[mi][ni], 0, 0, 0);  \
    }                                                                        \
    __builtin_amdgcn_s_setprio(0);                                           \
  }

  STAGE(0, 0)  // 4 loads in flight
#pragma unroll 1
  for (int t = 0; t < 15; ++t) {
    STAGE((t + 1) & 1, (t + 1) << 6)  // +4 loads (8 outstanding)
    asm volatile("s_waitcnt vmcnt(4)" ::: "memory");  // tile t landed
    __builtin_amdgcn_s_barrier();
    __builtin_amdgcn_sched_barrier(0);
    COMPUTE(t & 1)
    __builtin_amdgcn_sched_barrier(0);
    __builtin_amdgcn_s_barrier();  // reads of buf t done before overwrite
  }
  asm volatile("s_waitcnt vmcnt(0)" ::: "memory");
  __builtin_amdgcn_s_barrier();
  __builtin_amdgcn_sched_barrier(0);
  COMPUTE(1)

  // epilogue: bias + rope, write bf16
#pragma unroll
  for (int mi = 0; mi < 4; ++mi) {
#pragma unroll
    for (int ni = 0; ni < 4; ++ni) {
      const int n = n0 + (wc << 6) + (ni << 4) + (lane & 15);
      const float bn = bias[n];
      const int h = n >> 7, t = (n >> 6) & 1, d = n & 63;
      const int i2 = d >> 1;
      const bool ev = (d & 1) == 0;
#pragma unroll
      for (int r = 0; r < 4; ++r) {
        const int m = m0 + (wr << 6) + (mi << 4) + ((lane >> 4) << 2) + r;
        const int s = m & (SS - 1);
        const int bb = m >> 9;
        const float v = acc[mi][ni][r] + bn;
        const float p = __shfl_xor(v, 1);
        const float cs = ctab[(s << 5) + i2];
        const float sn = stab[(s << 5) + i2];
        const float o = ev ? (v * cs - p * sn) : (v * cs + p * sn);
        QK[((((size_t)bb * EN + h) * 2 + t) * SS + s) * DD + d] = f2bf(o);
      }
    }
  }
}

// ---- logits: per (b,h), 128x128 tiles of 512x512 (bf16 QK) ----
__global__ __launch_bounds__(256, 4) void logits_kernel(
    const unsigned short* __restrict__ QK, const float* __restrict__ pmask,
    float* __restrict__ out) {
  __shared__ __align__(16) unsigned char sm[32768];  // Q[128][64] | K[128][64]
  const int tid = threadIdx.x;
  const int lane = tid & 63;
  const int wid = tid >> 6;
  const int wr = wid >> 1, wc = wid & 1;
  const int f = blockIdx.x;
  const int wkr = (f & 7) * 288 + (f >> 3);
  const int bh = wkr >> 4;
  const int bb = bh / EN;
  const int tm = (wkr >> 2) & 3, tn = wkr & 3;
  const int mq0 = tm << 7, nk0 = tn << 7;
  const unsigned short* Qb = QK + (size_t)bh * 2 * SS * DD;
  const unsigned short* Kb = Qb + SS * DD;

#pragma unroll
  for (int it = 0; it < 4; ++it) {
    const int q = it * 256 + tid;
    const int r = q >> 3, cl = q & 7;
    const int cs = cl ^ (r & 7);
    __builtin_amdgcn_global_load_lds(
        GPTR(Qb + (size_t)(mq0 + r) * DD + (cs << 3)),
        LPTR(sm + ((it * 256 + wid * 64) << 4)), 16, 0, 0);
    __builtin_amdgcn_global_load_lds(
        GPTR(Kb + (size_t)(nk0 + r) * DD + (cs << 3)),
        LPTR(sm + 16384 + ((it * 256 + wid * 64) << 4)), 16, 0, 0);
  }
  __syncthreads();

  f32x4 acc[4][4];
#pragma unroll
  for (int i = 0; i < 4; ++i)
#pragma unroll
    for (int j = 0; j < 4; ++j) acc[i][j] = (f32x4){0.f, 0.f, 0.f, 0.f};

  typedef short bf16x8 __attribute__((ext_vector_type(8)));
#pragma unroll
  for (int kb = 0; kb < 2; ++kb) {
    bf16x8 af[4], bfr[4];
    const int ca = (kb << 2) + (lane >> 4);
#pragma unroll
    for (int i = 0; i < 4; ++i) {
      const int ra = (wr << 6) + (i << 4) + (lane & 15);
      af[i] = *(const bf16x8*)(sm + (ra << 7) + ((ca ^ (ra & 7)) << 4));
      const int rb = (wc << 6) + (i << 4) + (lane & 15);
      bfr[i] =
          *(const bf16x8*)(sm + 16384 + (rb << 7) + ((ca ^ (rb & 7)) << 4));
    }
#pragma unroll
    for (int mi = 0; mi < 4; ++mi)
#pragma unroll
      for (int ni = 0; ni < 4; ++ni)
        acc[mi][ni] = __builtin_amdgcn_mfma_f32_16x16x32_bf16(
            af[mi], bfr[ni], acc[mi][ni], 0, 0, 0);
  }

#pragma unroll
  for (int mi = 0; mi < 4; ++mi) {
#pragma unroll
    for (int ni = 0; ni < 4; ++ni) {
      const int n = nk0 + (wc << 6) + (ni << 4) + (lane & 15);
      const float pd = pmask[bb * SS + n];
      const float sub = (1.0f - pd) * 1e12f;
#pragma unroll
      for (int r = 0; r < 4; ++r) {
        const int m = mq0 + (wr << 6) + (mi << 4) + ((lane >> 4) << 2) + r;
        float v = acc[mi][ni][r] * pd - sub;
        if (m > n) v -= 1e12f;
        out[((size_t)bh * SS + m) * SS + n] = v * 0.125f;
      }
    }
  }
}

extern "C" void kernel_launch(void* const* d_in, const int* in_sizes, int n_in,
                              void* d_out, int out_size, void* d_ws,
                              size_t ws_size, hipStream_t stream) {
  const float* X = (const float*)d_in[0];
  const float* pm = (const float*)d_in[1];
  const float* W = (const float*)d_in[2];
  const float* bias = (const float*)d_in[3];
  float* out = (float*)d_out;
  unsigned char* ws = (unsigned char*)d_ws;
  unsigned short* QK = (unsigned short*)ws;      // 18,874,368 B
  unsigned char* Wf8 = ws + 18874368;            // 1,179,648 B
  float* ctab = (float*)(ws + 20054016);         // 65,536 B
  float* stab = (float*)(ws + 20119552);         // 65,536 B
  unsigned char* Xf8 = ws + 20185088;            // 8,388,608 B

  prep_kernel<<<dim3(1328), dim3(256), 0, stream>>>(W, X, Wf8, Xf8, ctab, stab);
  proj_rope_kernel<<<dim3(576), dim3(256), 0, stream>>>(Xf8, Wf8, bias, ctab,
                                                        stab, QK);
  logits_kernel<<<dim3(2304), dim3(256), 0, stream>>>(QK, pm, out);
}